// Round 3
// baseline (584.354 us; speedup 1.0000x reference)
//
#include <hip/hip_runtime.h>
#include <hip/hip_bf16.h>
#include <stdint.h>

// Problem dims (fixed by reference setup_inputs)
#define M_DIM 8192   // B*S = 4*2048
#define N_DIM 4096   // D_OUT
#define K_DIM 4096   // D_IN

typedef __hip_bfloat16 bf16;
typedef __attribute__((ext_vector_type(8))) short bf16x8;   // MFMA A/B frag (8 bf16 = 4 VGPRs)
typedef __attribute__((ext_vector_type(4))) float floatx4;  // MFMA C/D frag

__device__ __forceinline__ uint2 pack_bf16x4(float4 v) {
  bf16 b0 = __float2bfloat16(v.x);
  bf16 b1 = __float2bfloat16(v.y);
  bf16 b2 = __float2bfloat16(v.z);
  bf16 b3 = __float2bfloat16(v.w);
  unsigned int lo = (unsigned int)*(unsigned short*)&b0 |
                    ((unsigned int)*(unsigned short*)&b1 << 16);
  unsigned int hi = (unsigned int)*(unsigned short*)&b2 |
                    ((unsigned int)*(unsigned short*)&b3 << 16);
  return make_uint2(lo, hi);
}

// -------------------------------------------------------------------------
// Kernel 1 (merged aux): blocks [0, CAST_BLOCKS) cast x fp32->bf16
// (8 elems/thread); blocks [CAST_BLOCKS, ..) fake-quant W (INT2 per-128
// group min/max, 16 lanes/group, 8 elems/lane) and cast to bf16.
// -------------------------------------------------------------------------
#define CAST_BLOCKS ((M_DIM * K_DIM) / 8 / 256)    // 16384
#define QUANT_BLOCKS ((N_DIM * K_DIM) / 8 / 256)   // 8192

__global__ void aux_kernel(const float* __restrict__ x, bf16* __restrict__ xb,
                           const float* __restrict__ w, bf16* __restrict__ wq) {
  if (blockIdx.x < CAST_BLOCKS) {
    // ---- cast x ----
    const size_t base = (size_t)blockIdx.x * 512;  // float4 units
    const int tid = threadIdx.x;
    const float4* p = (const float4*)x + base;
    float4 a = p[tid];
    float4 b = p[tid + 256];
    uint2* q = (uint2*)xb + base;
    q[tid]       = pack_bf16x4(a);
    q[tid + 256] = pack_bf16x4(b);
  } else {
    // ---- fake-quant w ----
    const int t = (blockIdx.x - CAST_BLOCKS) * blockDim.x + threadIdx.x;
    const int g = t >> 4;        // group id (128 contiguous elems)
    const int s = t & 15;        // sub-lane within group

    const float4* p = (const float4*)(w + (size_t)g * 128);
    float4 a = p[s];             // elems s*4 .. s*4+3
    float4 b = p[s + 16];        // elems 64+s*4 .. 64+s*4+3

    float mn = fminf(fminf(fminf(a.x, a.y), fminf(a.z, a.w)),
                     fminf(fminf(b.x, b.y), fminf(b.z, b.w)));
    float mx = fmaxf(fmaxf(fmaxf(a.x, a.y), fmaxf(a.z, a.w)),
                     fmaxf(fmaxf(b.x, b.y), fmaxf(b.z, b.w)));
#pragma unroll
    for (int off = 8; off >= 1; off >>= 1) {
      mn = fminf(mn, __shfl_xor(mn, off));
      mx = fmaxf(mx, __shfl_xor(mx, off));
    }
    const float rng = mx - mn;
    float4 oa, ob;
    if (rng < 1e-8f) {
      oa = a; ob = b;            // pass-through for near-constant groups
    } else {
      const float scale = rng / 3.0f;  // max_q = 3 for INT2
      // exact division + rintf to match jnp.round semantics
      float q0 = fminf(fmaxf(rintf((a.x - mn) / scale), 0.f), 3.f);
      float q1 = fminf(fmaxf(rintf((a.y - mn) / scale), 0.f), 3.f);
      float q2 = fminf(fmaxf(rintf((a.z - mn) / scale), 0.f), 3.f);
      float q3 = fminf(fmaxf(rintf((a.w - mn) / scale), 0.f), 3.f);
      float q4 = fminf(fmaxf(rintf((b.x - mn) / scale), 0.f), 3.f);
      float q5 = fminf(fmaxf(rintf((b.y - mn) / scale), 0.f), 3.f);
      float q6 = fminf(fmaxf(rintf((b.z - mn) / scale), 0.f), 3.f);
      float q7 = fminf(fmaxf(rintf((b.w - mn) / scale), 0.f), 3.f);
      oa = make_float4(q0 * scale + mn, q1 * scale + mn, q2 * scale + mn, q3 * scale + mn);
      ob = make_float4(q4 * scale + mn, q5 * scale + mn, q6 * scale + mn, q7 * scale + mn);
    }
    uint2* q = (uint2*)(wq + (size_t)g * 128);
    q[s]      = pack_bf16x4(oa);
    q[s + 16] = pack_bf16x4(ob);
  }
}

// -------------------------------------------------------------------------
// Kernel 2: C[M,N] = A[M,K] * Bw[N,K]^T + bias, bf16 MFMA (m97 structure)
// with XCD-compact block swizzle: N partitioned into 8 strips of 4 N-tiles
// (strip = linear & 7 → one per XCD under round-robin dispatch); per-XCD
// B working set = 512 cols x 4096 x 2B = 4 MB = its L2, so B-tile re-reads
// (64x each) become L2 hits; within a strip blocks walk M-major so
// co-resident blocks share A-tiles.
// -------------------------------------------------------------------------
#define BM 128
#define BN 128
#define BK 64

typedef const uint32_t GQ __attribute__((address_space(1)));
typedef uint32_t LQ __attribute__((address_space(3)));

__global__ void gemm_bt_kernel(const bf16* __restrict__ A,   // [M,K] bf16
                               const bf16* __restrict__ Bw,  // [N,K] bf16
                               const float* __restrict__ bias,
                               float* __restrict__ C) {      // [M,N] fp32
  __shared__ bf16 sA[BM * BK];  // 16 KB
  __shared__ bf16 sB[BN * BK];  // 16 KB

  const int tid  = threadIdx.x;
  const int lane = tid & 63;
  const int warp = tid >> 6;   // 0..3
  const int wm   = warp & 1;   // wave row (M dir): 2 waves
  const int wn   = warp >> 1;  // wave col (N dir): 2 waves

  // XCD-compact swizzle (2048 blocks, 1-D launch)
  const int linear = blockIdx.x;
  const int strip  = linear & 7;        // XCD under round-robin dispatch
  const int within = linear >> 3;       // 0..255 per strip
  const int mt     = within & 63;       // M-major walk within strip
  const int nsub   = within >> 6;       // 0..3
  const int m0     = mt * BM;
  const int n0     = (strip * 4 + nsub) * BN;

  floatx4 acc[4][4];
#pragma unroll
  for (int i = 0; i < 4; ++i)
#pragma unroll
    for (int j = 0; j < 4; ++j)
      acc[i][j] = (floatx4){0.f, 0.f, 0.f, 0.f};

  // Staging geometry: one global_load_lds (16B/lane) covers 8 rows x 64 cols.
  const int srow = warp * 8 + (lane >> 3);
  const int scol = (lane & 7) * 8;

  // Fragment read geometry (16x16x32): m/n = lane&15, k = (lane>>4)*8 + j
  const int fr  = lane & 15;
  const int fk  = (lane >> 4) * 8;

  for (int k0 = 0; k0 < K_DIM; k0 += BK) {
#pragma unroll
    for (int j = 0; j < 4; ++j) {
      const int r = j * 32 + srow;
      const bf16* g = A + (size_t)(m0 + r) * K_DIM + (k0 + scol);
      bf16* l = sA + (j * 32 + warp * 8) * BK;  // wave-uniform LDS base
      __builtin_amdgcn_global_load_lds((GQ*)g, (LQ*)l, 16, 0, 0);
    }
#pragma unroll
    for (int j = 0; j < 4; ++j) {
      const int r = j * 32 + srow;
      const bf16* g = Bw + (size_t)(n0 + r) * K_DIM + (k0 + scol);
      bf16* l = sB + (j * 32 + warp * 8) * BK;
      __builtin_amdgcn_global_load_lds((GQ*)g, (LQ*)l, 16, 0, 0);
    }
    __syncthreads();

#pragma unroll
    for (int kk = 0; kk < BK; kk += 32) {
      bf16x8 af[4], bfr[4];
#pragma unroll
      for (int i = 0; i < 4; ++i)
        af[i] = *(const bf16x8*)&sA[(wm * 64 + i * 16 + fr) * BK + kk + fk];
#pragma unroll
      for (int j = 0; j < 4; ++j)
        bfr[j] = *(const bf16x8*)&sB[(wn * 64 + j * 16 + fr) * BK + kk + fk];
#pragma unroll
      for (int i = 0; i < 4; ++i)
#pragma unroll
        for (int j = 0; j < 4; ++j)
          acc[i][j] = __builtin_amdgcn_mfma_f32_16x16x32_bf16(af[i], bfr[j], acc[i][j], 0, 0, 0);
    }
    __syncthreads();
  }

  // Epilogue: C/D layout col=lane&15, row=(lane>>4)*4+reg
  const int cm = (lane >> 4) * 4;
  const int cn = lane & 15;
#pragma unroll
  for (int j = 0; j < 4; ++j) {
    const int col = n0 + wn * 64 + j * 16 + cn;
    const float bv = bias[col];
#pragma unroll
    for (int i = 0; i < 4; ++i) {
      const int rowb = m0 + wm * 64 + i * 16 + cm;
      float* out = C + (size_t)rowb * N_DIM + col;
#pragma unroll
      for (int r = 0; r < 4; ++r)
        out[(size_t)r * N_DIM] = acc[i][j][r] + bv;
    }
  }
}

// -------------------------------------------------------------------------
extern "C" void kernel_launch(void* const* d_in, const int* in_sizes, int n_in,
                              void* d_out, int out_size, void* d_ws, size_t ws_size,
                              hipStream_t stream) {
  const float* x      = (const float*)d_in[0];  // [4,2048,4096] fp32
  const float* weight = (const float*)d_in[1];  // [4096,4096] fp32
  const float* bias   = (const float*)d_in[2];  // [4096] fp32
  float* out          = (float*)d_out;          // [4,2048,4096] fp32

  // Workspace: wq bf16 [N,K] (32 MB) then xb bf16 [M,K] (64 MB)
  bf16* wq = (bf16*)d_ws;
  bf16* xb = (bf16*)((char*)d_ws + (size_t)N_DIM * K_DIM * sizeof(bf16));

  // 1) merged aux: cast X + fake-quant W
  aux_kernel<<<CAST_BLOCKS + QUANT_BLOCKS, 256, 0, stream>>>(x, xb, weight, wq);

  // 2) GEMM (1-D grid, swizzled internally)
  gemm_bt_kernel<<<(M_DIM / BM) * (N_DIM / BN), 256, 0, stream>>>(xb, wq, bias, out);
}

// Round 4
// 503.520 us; speedup vs baseline: 1.1605x; 1.1605x over previous
//
#include <hip/hip_runtime.h>
#include <hip/hip_bf16.h>
#include <stdint.h>

// Problem dims (fixed by reference setup_inputs)
#define M_DIM 8192   // B*S = 4*2048
#define N_DIM 4096   // D_OUT
#define K_DIM 4096   // D_IN

typedef __hip_bfloat16 bf16;
typedef __attribute__((ext_vector_type(8))) short bf16x8;   // MFMA A/B frag (8 bf16 = 4 VGPRs)
typedef __attribute__((ext_vector_type(4))) float floatx4;  // MFMA C/D frag

__device__ __forceinline__ uint2 pack_bf16x4(float4 v) {
  bf16 b0 = __float2bfloat16(v.x);
  bf16 b1 = __float2bfloat16(v.y);
  bf16 b2 = __float2bfloat16(v.z);
  bf16 b3 = __float2bfloat16(v.w);
  unsigned int lo = (unsigned int)*(unsigned short*)&b0 |
                    ((unsigned int)*(unsigned short*)&b1 << 16);
  unsigned int hi = (unsigned int)*(unsigned short*)&b2 |
                    ((unsigned int)*(unsigned short*)&b3 << 16);
  return make_uint2(lo, hi);
}

// -------------------------------------------------------------------------
// Kernel 1: fake-quant weight (INT2, per-128-group min/max) -> bf16.
// 16 lanes/group, 8 elems/lane (2x float4 coalesced), 4 shuffle levels.
// -------------------------------------------------------------------------
__global__ void quant_w_kernel(const float* __restrict__ w, bf16* __restrict__ wq) {
  const int t = blockIdx.x * blockDim.x + threadIdx.x;
  const int g = t >> 4;        // group id (128 contiguous elems)
  const int s = t & 15;        // sub-lane within group

  const float4* p = (const float4*)(w + (size_t)g * 128);
  float4 a = p[s];
  float4 b = p[s + 16];

  float mn = fminf(fminf(fminf(a.x, a.y), fminf(a.z, a.w)),
                   fminf(fminf(b.x, b.y), fminf(b.z, b.w)));
  float mx = fmaxf(fmaxf(fmaxf(a.x, a.y), fmaxf(a.z, a.w)),
                   fmaxf(fmaxf(b.x, b.y), fmaxf(b.z, b.w)));
#pragma unroll
  for (int off = 8; off >= 1; off >>= 1) {
    mn = fminf(mn, __shfl_xor(mn, off));
    mx = fmaxf(mx, __shfl_xor(mx, off));
  }
  const float rng = mx - mn;
  float4 oa, ob;
  if (rng < 1e-8f) {
    oa = a; ob = b;            // pass-through for near-constant groups
  } else {
    const float scale = rng / 3.0f;  // max_q = 3 for INT2
    float q0 = fminf(fmaxf(rintf((a.x - mn) / scale), 0.f), 3.f);
    float q1 = fminf(fmaxf(rintf((a.y - mn) / scale), 0.f), 3.f);
    float q2 = fminf(fmaxf(rintf((a.z - mn) / scale), 0.f), 3.f);
    float q3 = fminf(fmaxf(rintf((a.w - mn) / scale), 0.f), 3.f);
    float q4 = fminf(fmaxf(rintf((b.x - mn) / scale), 0.f), 3.f);
    float q5 = fminf(fmaxf(rintf((b.y - mn) / scale), 0.f), 3.f);
    float q6 = fminf(fmaxf(rintf((b.z - mn) / scale), 0.f), 3.f);
    float q7 = fminf(fmaxf(rintf((b.w - mn) / scale), 0.f), 3.f);
    oa = make_float4(q0 * scale + mn, q1 * scale + mn, q2 * scale + mn, q3 * scale + mn);
    ob = make_float4(q4 * scale + mn, q5 * scale + mn, q6 * scale + mn, q7 * scale + mn);
  }
  uint2* q = (uint2*)(wq + (size_t)g * 128);
  q[s]      = pack_bf16x4(oa);
  q[s + 16] = pack_bf16x4(ob);
}

// -------------------------------------------------------------------------
// Kernel 2: cast x fp32 -> bf16, 8 elems/thread
// -------------------------------------------------------------------------
__global__ void cast_x_kernel(const float* __restrict__ x, bf16* __restrict__ xb) {
  const size_t base = (size_t)blockIdx.x * 512;  // float4 units
  const int tid = threadIdx.x;
  const float4* p = (const float4*)x + base;
  float4 a = p[tid];
  float4 b = p[tid + 256];
  uint2* q = (uint2*)xb + base;
  q[tid]       = pack_bf16x4(a);
  q[tid + 256] = pack_bf16x4(b);
}

// -------------------------------------------------------------------------
// Kernel 3: C[M,N] = A[M,K] * Bw[N,K]^T + bias, bf16 MFMA.
// m97 structure (128x128 tile, BK=64, 2x2 waves, 4x4 16x16x32 frags) PLUS
// XOR-swizzled LDS layout to kill the structural 16-way ds_read_b128 bank
// conflict: logical (row, chunk16B) stored at physical chunk ^ (row&7).
//  - staging: global_load_lds forces physical placement = lane*16, so each
//    lane FETCHES global chunk (l&7)^((l>>3)&7) — same 128B segments,
//    still fully coalesced.
//  - frag reads: physical chunk = (k/8) ^ (row&7); each 8-lane group then
//    spans all 32 banks (residual 2-way alias is free).
// Grid: plain 2-D (blockIdx.x = N-tile fastest) — consecutive blocks share
// the A-strip; round-3's XCD-strip experiment tripled FETCH_SIZE, reverted.
// -------------------------------------------------------------------------
#define BM 128
#define BN 128
#define BK 64

typedef const uint32_t GQ __attribute__((address_space(1)));
typedef uint32_t LQ __attribute__((address_space(3)));

__global__ void gemm_bt_kernel(const bf16* __restrict__ A,   // [M,K] bf16
                               const bf16* __restrict__ Bw,  // [N,K] bf16
                               const float* __restrict__ bias,
                               float* __restrict__ C) {      // [M,N] fp32
  __shared__ bf16 sA[BM * BK];  // 16 KB
  __shared__ bf16 sB[BN * BK];  // 16 KB

  const int tid  = threadIdx.x;
  const int lane = tid & 63;
  const int warp = tid >> 6;   // 0..3
  const int wm   = warp & 1;   // wave row (M dir)
  const int wn   = warp >> 1;  // wave col (N dir)
  const int m0   = blockIdx.y * BM;
  const int n0   = blockIdx.x * BN;

  floatx4 acc[4][4];
#pragma unroll
  for (int i = 0; i < 4; ++i)
#pragma unroll
    for (int j = 0; j < 4; ++j)
      acc[i][j] = (floatx4){0.f, 0.f, 0.f, 0.f};

  // Staging: lane l covers physical (row = l>>3, chunkP = l&7) of an
  // 8-row x 64-col slab. It must fetch logical chunk = chunkP ^ (row&7).
  const int srow   = warp * 8 + (lane >> 3);
  const int schunk = (lane & 7) ^ ((lane >> 3) & 7);
  const int scol   = schunk * 8;

  // Fragment read geometry (16x16x32): row = lane&15, k = (lane>>4)*8 + j.
  // Physical chunk = (k/8) ^ (row&7) = ((kk>>3)+(lane>>4)) ^ (lane&7).
  const int fr  = lane & 15;
  const int fs  = lane & 7;     // row&7 for swizzle
  const int fc  = lane >> 4;    // k-chunk base

  for (int k0 = 0; k0 < K_DIM; k0 += BK) {
#pragma unroll
    for (int j = 0; j < 4; ++j) {
      const int r = j * 32 + srow;
      const bf16* g = A + (size_t)(m0 + r) * K_DIM + (k0 + scol);
      bf16* l = sA + (j * 32 + warp * 8) * BK;  // wave-uniform LDS base
      __builtin_amdgcn_global_load_lds((GQ*)g, (LQ*)l, 16, 0, 0);
    }
#pragma unroll
    for (int j = 0; j < 4; ++j) {
      const int r = j * 32 + srow;
      const bf16* g = Bw + (size_t)(n0 + r) * K_DIM + (k0 + scol);
      bf16* l = sB + (j * 32 + warp * 8) * BK;
      __builtin_amdgcn_global_load_lds((GQ*)g, (LQ*)l, 16, 0, 0);
    }
    __syncthreads();

#pragma unroll
    for (int kk = 0; kk < BK; kk += 32) {
      const int chnk = (((kk >> 3) + fc) ^ fs) * 8;
      bf16x8 af[4], bfr[4];
#pragma unroll
      for (int i = 0; i < 4; ++i)
        af[i] = *(const bf16x8*)&sA[(wm * 64 + i * 16 + fr) * BK + chnk];
#pragma unroll
      for (int j = 0; j < 4; ++j)
        bfr[j] = *(const bf16x8*)&sB[(wn * 64 + j * 16 + fr) * BK + chnk];
#pragma unroll
      for (int i = 0; i < 4; ++i)
#pragma unroll
        for (int j = 0; j < 4; ++j)
          acc[i][j] = __builtin_amdgcn_mfma_f32_16x16x32_bf16(af[i], bfr[j], acc[i][j], 0, 0, 0);
    }
    __syncthreads();
  }

  // Epilogue: C/D layout col=lane&15, row=(lane>>4)*4+reg
  const int cm = (lane >> 4) * 4;
  const int cn = lane & 15;
#pragma unroll
  for (int j = 0; j < 4; ++j) {
    const int col = n0 + wn * 64 + j * 16 + cn;
    const float bv = bias[col];
#pragma unroll
    for (int i = 0; i < 4; ++i) {
      const int rowb = m0 + wm * 64 + i * 16 + cm;
      float* out = C + (size_t)rowb * N_DIM + col;
#pragma unroll
      for (int r = 0; r < 4; ++r)
        out[(size_t)r * N_DIM] = acc[i][j][r] + bv;
    }
  }
}

// -------------------------------------------------------------------------
extern "C" void kernel_launch(void* const* d_in, const int* in_sizes, int n_in,
                              void* d_out, int out_size, void* d_ws, size_t ws_size,
                              hipStream_t stream) {
  const float* x      = (const float*)d_in[0];  // [4,2048,4096] fp32
  const float* weight = (const float*)d_in[1];  // [4096,4096] fp32
  const float* bias   = (const float*)d_in[2];  // [4096] fp32
  float* out          = (float*)d_out;          // [4,2048,4096] fp32

  // Workspace: wq bf16 [N,K] (32 MB) then xb bf16 [M,K] (64 MB)
  bf16* wq = (bf16*)d_ws;
  bf16* xb = (bf16*)((char*)d_ws + (size_t)N_DIM * K_DIM * sizeof(bf16));

  // 1) fake-quant + cast W
  {
    int threads = (N_DIM * K_DIM) / 8;
    quant_w_kernel<<<threads / 256, 256, 0, stream>>>(weight, wq);
  }
  // 2) cast X
  {
    int threads = (M_DIM * K_DIM) / 8;
    cast_x_kernel<<<threads / 256, 256, 0, stream>>>(x, xb);
  }
  // 3) GEMM (2-D grid: N-tiles fastest → co-resident blocks share A-strip)
  {
    dim3 grid(N_DIM / BN, M_DIM / BM);  // 32 x 64
    gemm_bt_kernel<<<grid, 256, 0, stream>>>(xb, wq, bias, out);
  }
}